// Round 1
// baseline (173.236 us; speedup 1.0000x reference)
//
#include <hip/hip_runtime.h>
#include <hip/hip_bf16.h>
#include <math.h>

typedef __bf16 bf16x8 __attribute__((ext_vector_type(8)));
typedef float f32x4 __attribute__((ext_vector_type(4)));

#define N_TOT 8192
#define HALF_N 4096
#define D 128
#define INV_T 14.285714285714286f

// ---------- kernel 1: fp32 -> bf16 (RNE) ----------
__device__ __forceinline__ unsigned short f2bf(float f) {
    union { float f; unsigned int u; } a; a.f = f;
    unsigned int u = a.u;
    unsigned int r = (u + 0x7fffu + ((u >> 16) & 1u)) >> 16;
    return (unsigned short)r;
}

__global__ void cvt_kernel(const float* __restrict__ in, unsigned short* __restrict__ out) {
    int i = blockIdx.x * blockDim.x + threadIdx.x;  // each thread: 4 elements
    float4 v = reinterpret_cast<const float4*>(in)[i];
    ushort4 o;
    o.x = f2bf(v.x); o.y = f2bf(v.y); o.z = f2bf(v.z); o.w = f2bf(v.w);
    reinterpret_cast<ushort4*>(out)[i] = o;
}

// ---------- kernel 2: fused sim + online logsumexp ----------
// Block: 256 threads = 4 waves. Block owns 32 rows (2 row-tiles of 16).
// Wave w covers columns [w*2048, (w+1)*2048) in 16-col tiles.
// MFMA 16x16x32 bf16; C/D layout: row=(lane>>4)*4+reg, col=lane&15.
__global__ __launch_bounds__(256)
void simclr_kernel(const unsigned short* __restrict__ Fb, float* __restrict__ rowout) {
    const int tid  = threadIdx.x;
    const int lane = tid & 63;
    const int wid  = tid >> 6;
    const int lr   = lane & 15;   // A: row-in-tile; B: col-in-tile
    const int lg   = lane >> 4;   // k-group (0..3)
    const int row0 = blockIdx.x * 32;

    // A fragments: rows row0 + rt*16 + lr, k = kk*32 + lg*8 .. +8
    bf16x8 a[2][4];
#pragma unroll
    for (int rt = 0; rt < 2; ++rt)
#pragma unroll
        for (int kk = 0; kk < 4; ++kk)
            a[rt][kk] = *reinterpret_cast<const bf16x8*>(
                Fb + (size_t)(row0 + rt * 16 + lr) * D + kk * 32 + lg * 8);

    float m[2][4], s[2][4], pv[2][4];
#pragma unroll
    for (int rt = 0; rt < 2; ++rt)
#pragma unroll
        for (int r = 0; r < 4; ++r) {
            m[rt][r]  = -INFINITY;
            s[rt][r]  = 0.f;
            pv[rt][r] = -INFINITY;
        }

    const int c0beg = wid * 2048;
#pragma unroll 1
    for (int c0 = c0beg; c0 < c0beg + 2048; c0 += 16) {
        bf16x8 b[4];
#pragma unroll
        for (int kk = 0; kk < 4; ++kk)
            b[kk] = *reinterpret_cast<const bf16x8*>(
                Fb + (size_t)(c0 + lr) * D + kk * 32 + lg * 8);

        f32x4 acc[2];
        acc[0] = {0.f, 0.f, 0.f, 0.f};
        acc[1] = {0.f, 0.f, 0.f, 0.f};
#pragma unroll
        for (int kk = 0; kk < 4; ++kk) {
            acc[0] = __builtin_amdgcn_mfma_f32_16x16x32_bf16(a[0][kk], b[kk], acc[0], 0, 0, 0);
            acc[1] = __builtin_amdgcn_mfma_f32_16x16x32_bf16(a[1][kk], b[kk], acc[1], 0, 0, 0);
        }

        const int col = c0 + lr;
#pragma unroll
        for (int rt = 0; rt < 2; ++rt) {
            const int rowb = row0 + rt * 16 + lg * 4;
#pragma unroll
            for (int r = 0; r < 4; ++r) {
                const int row = rowb + r;
                const float v = acc[rt][r] * INV_T;
                if (col == (row ^ HALF_N)) pv[rt][r] = v;   // positive (kept in lse too)
                if (col != row) {                            // exclude diagonal
                    const float mo = m[rt][r];
                    const float mn = fmaxf(mo, v);
                    s[rt][r] = s[rt][r] * __expf(mo - mn) + __expf(v - mn);
                    m[rt][r] = mn;
                }
            }
        }
    }

    // intra-wave reduce: butterfly across the 16 lanes of each k-group
#pragma unroll
    for (int off = 1; off < 16; off <<= 1) {
#pragma unroll
        for (int rt = 0; rt < 2; ++rt)
#pragma unroll
            for (int r = 0; r < 4; ++r) {
                const float mo = __shfl_xor(m[rt][r], off, 64);
                const float so = __shfl_xor(s[rt][r], off, 64);
                const float po = __shfl_xor(pv[rt][r], off, 64);
                const float mn = fmaxf(m[rt][r], mo);
                s[rt][r] = s[rt][r] * __expf(m[rt][r] - mn) + so * __expf(mo - mn);
                m[rt][r] = mn;
                pv[rt][r] = fmaxf(pv[rt][r], po);
            }
    }

    // cross-wave reduce via LDS
    __shared__ float red_m[4][32], red_s[4][32], red_p[4][32];
    if (lr == 0) {
#pragma unroll
        for (int rt = 0; rt < 2; ++rt)
#pragma unroll
            for (int r = 0; r < 4; ++r) {
                const int rl = rt * 16 + lg * 4 + r;
                red_m[wid][rl] = m[rt][r];
                red_s[wid][rl] = s[rt][r];
                red_p[wid][rl] = pv[rt][r];
            }
    }
    __syncthreads();
    if (tid < 32) {
        float M = red_m[0][tid], S = red_s[0][tid], P = red_p[0][tid];
#pragma unroll
        for (int w = 1; w < 4; ++w) {
            const float mo = red_m[w][tid], so = red_s[w][tid];
            const float mn = fmaxf(M, mo);
            S = S * __expf(M - mn) + so * __expf(mo - mn);
            M = mn;
            P = fmaxf(P, red_p[w][tid]);
        }
        rowout[row0 + tid] = M + __logf(S) - P;
    }
}

// ---------- kernel 3: mean over 8192 rows ----------
__global__ void reduce_kernel(const float* __restrict__ rows, float* __restrict__ out) {
    float s = 0.f;
    for (int i = threadIdx.x; i < N_TOT; i += 256) s += rows[i];
#pragma unroll
    for (int off = 32; off > 0; off >>= 1) s += __shfl_down(s, off, 64);
    __shared__ float ls[4];
    if ((threadIdx.x & 63) == 0) ls[threadIdx.x >> 6] = s;
    __syncthreads();
    if (threadIdx.x == 0) out[0] = (ls[0] + ls[1] + ls[2] + ls[3]) * (1.0f / (float)N_TOT);
}

extern "C" void kernel_launch(void* const* d_in, const int* in_sizes, int n_in,
                              void* d_out, int out_size, void* d_ws, size_t ws_size,
                              hipStream_t stream) {
    const float* feat = (const float*)d_in[0];
    unsigned short* fb = (unsigned short*)d_ws;                       // 8192*128 bf16 = 2 MB
    float* rows = (float*)((char*)d_ws + (size_t)N_TOT * D * 2);      // 8192 f32 = 32 KB
    float* out = (float*)d_out;

    cvt_kernel<<<(N_TOT * D / 4) / 256, 256, 0, stream>>>(feat, fb);
    simclr_kernel<<<N_TOT / 32, 256, 0, stream>>>(fb, rows);
    reduce_kernel<<<1, 256, 0, stream>>>(rows, out);
}

// Round 2
// 63.263 us; speedup vs baseline: 2.7383x; 2.7383x over previous
//
#include <hip/hip_runtime.h>
#include <hip/hip_bf16.h>
#include <math.h>

typedef __bf16 bf16x8 __attribute__((ext_vector_type(8)));
typedef float f32x4 __attribute__((ext_vector_type(4)));

#define N_TOT 8192
#define HALF_N 4096
#define D 128
#define INV_T 14.285714285714286f
#define CSC 20.60992915555662f   /* (1/0.07) * log2(e) */
#define LN2F 0.69314718055994531f
#define NEG_BIG -1.0e38f
#define CS 8                      /* column splits */

__device__ __forceinline__ unsigned short f2bf(float f) {
    union { float f; unsigned int u; } a; a.f = f;
    unsigned int u = a.u;
    return (unsigned short)((u + 0x7fffu + ((u >> 16) & 1u)) >> 16);
}

// ---------- kernel 1: fused fp32->bf16 cvt  +  positive dots ----------
__global__ __launch_bounds__(256)
void prep_kernel(const float* __restrict__ in, unsigned short* __restrict__ fb,
                 float* __restrict__ posb) {
    const int bid = blockIdx.x;
    if (bid < 1024) {
        int i = bid * 256 + threadIdx.x;          // 4 floats per thread
        float4 v = reinterpret_cast<const float4*>(in)[i];
        ushort4 o;
        o.x = f2bf(v.x); o.y = f2bf(v.y); o.z = f2bf(v.z); o.w = f2bf(v.w);
        reinterpret_cast<ushort4*>(fb)[i] = o;
    } else {
        // one wave per row: pos_i = dot(f_i, f_{i^4096}) * (1/T)   (nat units)
        const int row  = (bid - 1024) * 4 + (threadIdx.x >> 6);
        const int lane = threadIdx.x & 63;
        const float2 a = reinterpret_cast<const float2*>(in + (size_t)row * D)[lane];
        const float2 b = reinterpret_cast<const float2*>(in + (size_t)(row ^ HALF_N) * D)[lane];
        float dot = a.x * b.x + a.y * b.y;
#pragma unroll
        for (int off = 32; off > 0; off >>= 1) dot += __shfl_xor(dot, off, 64);
        if (lane == 0) posb[row] = dot * INV_T;
    }
}

// ---------- kernel 2: fused sim + partial logsumexp (log2 domain) ----------
// grid (128 row-blocks, 8 col-splits), 256 threads = 4 waves.
// Block: 64 rows (4 row-tiles) x 1024 cols; wave w: 256 cols = 16 tiles.
__global__ __launch_bounds__(256)
void simclr_kernel(const unsigned short* __restrict__ Fb,
                   float* __restrict__ pm, float* __restrict__ ps) {
    const int tid  = threadIdx.x;
    const int lane = tid & 63;
    const int wid  = tid >> 6;
    const int lr   = lane & 15;
    const int lg   = lane >> 4;
    const int row0 = blockIdx.x * 64;
    const int split = blockIdx.y;
    const int cbase = split * 1024 + wid * 256;

    // A fragments (also used as B-pattern for other blocks): rows row0+rt*16+lr
    bf16x8 a[4][4];
#pragma unroll
    for (int rt = 0; rt < 4; ++rt)
#pragma unroll
        for (int kk = 0; kk < 4; ++kk)
            a[rt][kk] = *reinterpret_cast<const bf16x8*>(
                Fb + (size_t)(row0 + rt * 16 + lr) * D + kk * 32 + lg * 8);

    float m[4][4], s[4][4];
#pragma unroll
    for (int rt = 0; rt < 4; ++rt)
#pragma unroll
        for (int r = 0; r < 4; ++r) { m[rt][r] = 0.f; s[rt][r] = 0.f; }

    bf16x8 b0[4], b1[4];
#pragma unroll
    for (int kk = 0; kk < 4; ++kk) {
        b0[kk] = *reinterpret_cast<const bf16x8*>(
            Fb + (size_t)(cbase + lr) * D + kk * 32 + lg * 8);
        b1[kk] = *reinterpret_cast<const bf16x8*>(
            Fb + (size_t)(cbase + 16 + lr) * D + kk * 32 + lg * 8);
    }

#pragma unroll 1
    for (int t = 0; t < 16; t += 2) {
        const int c0 = cbase + t * 16;

        f32x4 accA[4], accB[4];
#pragma unroll
        for (int rt = 0; rt < 4; ++rt) accA[rt] = {0.f, 0.f, 0.f, 0.f};
#pragma unroll
        for (int kk = 0; kk < 4; ++kk)
#pragma unroll
            for (int rt = 0; rt < 4; ++rt)
                accA[rt] = __builtin_amdgcn_mfma_f32_16x16x32_bf16(a[rt][kk], b0[kk], accA[rt], 0, 0, 0);

        if (t + 2 < 16) {
#pragma unroll
            for (int kk = 0; kk < 4; ++kk)
                b0[kk] = *reinterpret_cast<const bf16x8*>(
                    Fb + (size_t)(c0 + 32 + lr) * D + kk * 32 + lg * 8);
        }

#pragma unroll
        for (int rt = 0; rt < 4; ++rt) accB[rt] = {0.f, 0.f, 0.f, 0.f};
#pragma unroll
        for (int kk = 0; kk < 4; ++kk)
#pragma unroll
            for (int rt = 0; rt < 4; ++rt)
                accB[rt] = __builtin_amdgcn_mfma_f32_16x16x32_bf16(a[rt][kk], b1[kk], accB[rt], 0, 0, 0);

        if (t + 3 < 16) {
#pragma unroll
            for (int kk = 0; kk < 4; ++kk)
                b1[kk] = *reinterpret_cast<const bf16x8*>(
                    Fb + (size_t)(c0 + 48 + lr) * D + kk * 32 + lg * 8);
        }

        // per-element online lse update, batch-2 (one max3, 3 exp2 per 2 elems)
#pragma unroll
        for (int rt = 0; rt < 4; ++rt) {
            const bool dA = (c0 == row0 + rt * 16);        // wave-uniform
            const bool dB = (c0 + 16 == row0 + rt * 16);   // wave-uniform
#pragma unroll
            for (int r = 0; r < 4; ++r) {
                float v1 = accA[rt][r] * CSC;
                float v2 = accB[rt][r] * CSC;
                if (dA) { if (lr == lg * 4 + r) v1 = NEG_BIG; }  // drop diagonal
                if (dB) { if (lr == lg * 4 + r) v2 = NEG_BIG; }
                const float mo = m[rt][r];
                const float mn = fmaxf(fmaxf(mo, v1), v2);       // v_max3
                const float e0 = __builtin_amdgcn_exp2f(mo - mn);
                const float e1 = __builtin_amdgcn_exp2f(v1 - mn);
                const float e2 = __builtin_amdgcn_exp2f(v2 - mn);
                s[rt][r] = fmaf(s[rt][r], e0, e1 + e2);
                m[rt][r] = mn;
            }
        }
    }

    // two-phase butterfly across the 16 lr lanes (same rows, disjoint cols)
    __shared__ float red_m[4][64], red_s[4][64];
#pragma unroll
    for (int rt = 0; rt < 4; ++rt)
#pragma unroll
        for (int r = 0; r < 4; ++r) {
            float M = m[rt][r];
#pragma unroll
            for (int off = 1; off < 16; off <<= 1) M = fmaxf(M, __shfl_xor(M, off, 64));
            float sc = s[rt][r] * __builtin_amdgcn_exp2f(m[rt][r] - M);
#pragma unroll
            for (int off = 1; off < 16; off <<= 1) sc += __shfl_xor(sc, off, 64);
            if (lr == 0) {
                red_m[wid][rt * 16 + lg * 4 + r] = M;
                red_s[wid][rt * 16 + lg * 4 + r] = sc;
            }
        }
    __syncthreads();

    if (tid < 64) {  // merge the 4 waves' col-quarters; one partial per row
        float M = red_m[0][tid], S = red_s[0][tid];
#pragma unroll
        for (int w = 1; w < 4; ++w) {
            const float Mo = red_m[w][tid], So = red_s[w][tid];
            const float mn = fmaxf(M, Mo);
            S = fmaf(S, __builtin_amdgcn_exp2f(M - mn), So * __builtin_amdgcn_exp2f(Mo - mn));
            M = mn;
        }
        pm[split * N_TOT + row0 + tid] = M;
        ps[split * N_TOT + row0 + tid] = S;
    }
}

// ---------- kernel 3: merge splits, row losses, mean ----------
__global__ __launch_bounds__(1024)
void finalize_kernel(const float* __restrict__ pm, const float* __restrict__ ps,
                     const float* __restrict__ posb, float* __restrict__ out) {
    const int tid = threadIdx.x;
    float acc = 0.f;
    for (int i = tid; i < N_TOT; i += 1024) {
        float M = pm[i], S = ps[i];
#pragma unroll
        for (int k = 1; k < CS; ++k) {
            const float Mo = pm[k * N_TOT + i], So = ps[k * N_TOT + i];
            const float mn = fmaxf(M, Mo);
            S = fmaf(S, __builtin_amdgcn_exp2f(M - mn), So * __builtin_amdgcn_exp2f(Mo - mn));
            M = mn;
        }
        acc += LN2F * (M + __builtin_amdgcn_logf(S)) - posb[i];
    }
#pragma unroll
    for (int off = 32; off > 0; off >>= 1) acc += __shfl_xor(acc, off, 64);
    __shared__ float ls[16];
    if ((tid & 63) == 0) ls[tid >> 6] = acc;
    __syncthreads();
    if (tid == 0) {
        float t = 0.f;
#pragma unroll
        for (int w = 0; w < 16; ++w) t += ls[w];
        out[0] = t * (1.0f / (float)N_TOT);
    }
}

extern "C" void kernel_launch(void* const* d_in, const int* in_sizes, int n_in,
                              void* d_out, int out_size, void* d_ws, size_t ws_size,
                              hipStream_t stream) {
    const float* feat = (const float*)d_in[0];
    char* ws = (char*)d_ws;
    unsigned short* fb = (unsigned short*)ws;                         // 2 MB
    float* pm   = (float*)(ws + (size_t)N_TOT * D * 2);               // 256 KB
    float* ps   = (float*)(ws + (size_t)N_TOT * D * 2 + CS * N_TOT * 4);       // 256 KB
    float* posb = (float*)(ws + (size_t)N_TOT * D * 2 + 2 * CS * N_TOT * 4);   // 32 KB
    float* out = (float*)d_out;

    prep_kernel<<<3072, 256, 0, stream>>>(feat, fb, posb);
    simclr_kernel<<<dim3(128, CS), 256, 0, stream>>>(fb, pm, ps);
    finalize_kernel<<<1, 1024, 0, stream>>>(pm, ps, posb, out);
}